// Round 15
// baseline (515.205 us; speedup 1.0000x reference)
//
#include <hip/hip_runtime.h>
#include <hip/hip_bf16.h>
#include <cstdint>
#include <cstddef>

typedef __bf16 bf16x8 __attribute__((ext_vector_type(8)));
typedef float  f32x4  __attribute__((ext_vector_type(4)));

typedef const __attribute__((address_space(1))) unsigned int gu32;
typedef __attribute__((address_space(3))) unsigned int lu32;

static __device__ __forceinline__ float bf2f(unsigned short u){
  unsigned v = ((unsigned)u) << 16;
  return __builtin_bit_cast(float, v);
}
static __device__ __forceinline__ unsigned short f2bf_bits(float f){
  __bf16 h = (__bf16)f;
  return __builtin_bit_cast(unsigned short, h);
}

// ---- K_pre: blocks 0..24 scatter edges -> Straw,rcnt; blocks 25..88 xb -------
__global__ __launch_bounds__(1024) void k_pre(const int* __restrict__ ei,
                                              const float* __restrict__ ea,
                                              int E, float* __restrict__ Straw,
                                              float* __restrict__ rcnt,
                                              const float* __restrict__ x,
                                              unsigned char* __restrict__ Xb){
  const int t = threadIdx.x;
  if (blockIdx.x < 25){
    __shared__ float Ssh[8*200];
    __shared__ float csh[200];
    __shared__ int nzsh;
    const int s0 = blockIdx.x * 8;
    if (t == 0) nzsh = 0;
    for (int i = t; i < 1600; i += 1024) Ssh[i] = 0.f;
    if (t < 200) csh[t] = 0.f;
    __syncthreads();
    if (t < 256){ if (ei[2*t + 1] != 0) atomicOr(&nzsh, 1); }
    __syncthreads();
    const int is64 = (nzsh == 0);
    const bool do_cnt = (blockIdx.x == 0);
    for (int e = t; e < E; e += 1024){
      int s, d;
      if (is64){ s = ei[2*e]; d = ei[2*(E+e)]; }
      else     { s = ei[e];   d = ei[E+e];     }
      if ((unsigned)s < 200u && (unsigned)d < 200u){
        if (do_cnt) atomicAdd(&csh[d], 1.f);
        unsigned ls = (unsigned)(s - s0);
        if (ls < 8u) atomicAdd(&Ssh[ls*200 + d], ea[e]);
      }
    }
    __syncthreads();
    for (int i = t; i < 1600; i += 1024)
      Straw[(size_t)s0*200 + i] = Ssh[i];
    if (do_cnt && t < 200) rcnt[t] = 1.f / fmaxf(csh[t], 1.f);
  } else {
    int idx0 = (blockIdx.x - 25)*1024 + t;
    for (int idx = idx0; idx < 256*2048; idx += 64*1024){
      int r  = idx >> 11;
      int sl = idx & 2047;
      int kc = sl >> 3, s = sl & 7;
      float4 v0 = {0.f,0.f,0.f,0.f}, v1 = {0.f,0.f,0.f,0.f};
      if (r < 200){
        const float* p = x + (size_t)r*16384 + kc*64 + s*8;
        v0 = *(const float4*)p;
        v1 = *(const float4*)(p + 4);
      }
      union { uint4 u; __bf16 h[8]; } pk;
      pk.h[0]=(__bf16)v0.x; pk.h[1]=(__bf16)v0.y; pk.h[2]=(__bf16)v0.z; pk.h[3]=(__bf16)v0.w;
      pk.h[4]=(__bf16)v1.x; pk.h[5]=(__bf16)v1.y; pk.h[6]=(__bf16)v1.z; pk.h[7]=(__bf16)v1.w;
      *(uint4*)(Xb + (size_t)r*32768 + kc*128 + ((s ^ (r & 7)) << 4)) = pk.u;
    }
  }
}

// ---------------- GEMM: Cpart[ks][224][NOUT] = A(256pad x K) * [Wl;Wr]^T -------
template<int BN, int KSPLIT, int KDIM, int NOUT, int NITER, int NTHREADS, bool NT>
__global__ __launch_bounds__(NTHREADS, 1024/NTHREADS/2)
void k_gemm(const unsigned char* __restrict__ Asrc,
            const float* __restrict__ Wl,
            const float* __restrict__ Wr,
            unsigned short* __restrict__ Cpart){
  constexpr int ROWB = KDIM * 2;
  constexpr int NT2  = (NOUT/2) / BN;
  constexpr int NS   = 2;
  constexpr int NB   = 8;
  constexpr int AJ   = 32768 / (NTHREADS*16);
  constexpr int VMC  = 8 + AJ;
  static_assert(BN/32 == NTHREADS/64, "wave owns 32 cols");
  static_assert(VMC == 12 || VMC == 16, "vmcnt literal");
  __shared__ unsigned char Lds[2][256*128];

  const int tid  = threadIdx.x;
  const int lane = tid & 63, wid = tid >> 6;
  const int l15  = lane & 15, lk = lane >> 4;
  const int bid  = blockIdx.x;
  const int ks    = bid & (KSPLIT - 1);
  const int ntile = bid / KSPLIT;
  const float* W = (ntile < NT2) ? (Wl + (size_t)ntile*BN*KDIM)
                                 : (Wr + (size_t)(ntile - NT2)*BN*KDIM);
  const int kc0   = ks * NITER;
  const int phase = ntile & (NITER - 1);
  auto kcAt = [&](int i){ return kc0 + ((i + phase) & (NITER - 1)); };

  const float* WB = W + (size_t)(wid*32 + l15)*KDIM + lk*8;
  f32x4 b0[NB], b1[NB];

  auto issueB = [&](f32x4 (&b)[NB], int kc){
    const float* p = WB + (size_t)kc*64;
    #pragma unroll
    for (int ns = 0; ns < NS; ns++)
      #pragma unroll
      for (int kst = 0; kst < 2; kst++){
        const f32x4* q = (const f32x4*)(p + (size_t)ns*16*KDIM + kst*32);
        if constexpr (NT){
          b[(ns*2+kst)*2 + 0] = __builtin_nontemporal_load(q);
          b[(ns*2+kst)*2 + 1] = __builtin_nontemporal_load(q + 1);
        } else {
          b[(ns*2+kst)*2 + 0] = *q;
          b[(ns*2+kst)*2 + 1] = *(q + 1);
        }
      }
    __builtin_amdgcn_sched_barrier(0);
  };

  const unsigned char* AG = Asrc + (size_t)(tid >> 3)*ROWB + (tid & 7)*16;
  auto issueA = [&](unsigned char* buf, int kc){
    const unsigned char* g = AG + (size_t)kc*128;
    #pragma unroll
    for (int j = 0; j < AJ; j++){
      __builtin_amdgcn_global_load_lds(
          (gu32*)(g + (size_t)j*(NTHREADS/8)*ROWB),
          (lu32*)(buf + j*(NTHREADS*16) + wid*1024),
          16, 0, 0);
    }
    __builtin_amdgcn_sched_barrier(0);
  };

  bf16x8 frag[NS*2];
  auto cvtB = [&](const f32x4 (&b)[NB]){
    #pragma unroll
    for (int f = 0; f < NS*2; f++){
      f32x4 lo = b[f*2], hi = b[f*2+1];
      bf16x8 v;
      v[0]=(__bf16)lo[0]; v[1]=(__bf16)lo[1]; v[2]=(__bf16)lo[2]; v[3]=(__bf16)lo[3];
      v[4]=(__bf16)hi[0]; v[5]=(__bf16)hi[1]; v[6]=(__bf16)hi[2]; v[7]=(__bf16)hi[3];
      frag[f] = v;
    }
  };

  f32x4 acc[14][NS];
  #pragma unroll
  for (int mt = 0; mt < 14; mt++)
    #pragma unroll
    for (int ns = 0; ns < NS; ns++)
      acc[mt][ns] = (f32x4){0.f,0.f,0.f,0.f};

  auto compute = [&](const unsigned char* buf){
    #pragma unroll
    for (int kst = 0; kst < 2; kst++){
      const int sx = (((kst*4 + lk) ^ (l15 & 7)) << 4);
      #pragma unroll
      for (int mt = 0; mt < 14; mt++){
        bf16x8 af = *(const bf16x8*)(buf + (mt*16 + l15)*128 + sx);
        #pragma unroll
        for (int ns = 0; ns < NS; ns++)
          acc[mt][ns] = __builtin_amdgcn_mfma_f32_16x16x32_bf16(af, frag[ns*2+kst], acc[mt][ns], 0, 0, 0);
      }
    }
  };

  auto STAGE = [&](f32x4 (&bc)[NB], unsigned char* Lc, int i){
    if (i + 1 < NITER){
      if constexpr (VMC == 12) asm volatile("s_waitcnt vmcnt(12) lgkmcnt(0)" ::: "memory");
      else                     asm volatile("s_waitcnt vmcnt(16) lgkmcnt(0)" ::: "memory");
    } else {
      asm volatile("s_waitcnt vmcnt(0) lgkmcnt(0)" ::: "memory");
    }
    __builtin_amdgcn_s_barrier();
    __builtin_amdgcn_sched_barrier(0);
    cvtB(bc);
    if (i + 2 < NITER) issueB(bc, kcAt(i + 2));
    __builtin_amdgcn_sched_barrier(0);
    compute(Lc);
    __builtin_amdgcn_s_barrier();
    __builtin_amdgcn_sched_barrier(0);
    if (i + 2 < NITER) issueA(Lc, kcAt(i + 2));
  };

  issueB(b0, kcAt(0)); issueA(Lds[0], kcAt(0));
  issueB(b1, kcAt(1)); issueA(Lds[1], kcAt(1));

  for (int i = 0; i < NITER; i += 2){
    STAGE(b0, Lds[0], i);
    STAGE(b1, Lds[1], i + 1);
  }

  const int rbase = ks * 224;
  const int cbase = ntile*BN + wid*32;
  #pragma unroll
  for (int mt = 0; mt < 14; mt++)
    #pragma unroll
    for (int ns = 0; ns < NS; ns++)
      #pragma unroll
      for (int j = 0; j < 4; j++){
        int row = mt*16 + lk*4 + j;
        int col = cbase + ns*16 + l15;
        Cpart[(size_t)(rbase + row)*NOUT + col] = f2bf_bits(acc[mt][ns][j]);
      }
}

// ---- k_h1r: fused reduce8 + h1 -> H1b (swizzled bf16) + zero-tail -------------
__global__ __launch_bounds__(256) void k_h1r(const unsigned short* __restrict__ Cp1,
                                             const float* __restrict__ Straw,
                                             const float* __restrict__ rcnt,
                                             const float* __restrict__ b1,
                                             unsigned char* __restrict__ H1b){
  __shared__ float PQsh[200*64];
  __shared__ float Qsh[50*64];
  __shared__ float Ssh[200*50];
  __shared__ float rcl[50];
  const int och = blockIdx.x >> 2, nsp = blockIdx.x & 3;
  const int t = threadIdx.x;
  constexpr size_t PART = (size_t)224*8192;

  if (t < 50) rcl[t] = rcnt[nsp*50 + t];
  __syncthreads();
  for (int i = t; i < 200*50; i += 256){
    int s = i / 50, j = i - s*50;
    Ssh[i] = Straw[s*200 + nsp*50 + j] * rcl[j];
  }
  for (int pi = t; pi < 1600; pi += 256){
    int s = pi >> 3, ch = pi & 7;
    const unsigned short* base = Cp1 + (size_t)s*8192 + och*64 + ch*8;
    float a[8] = {0.f,0.f,0.f,0.f,0.f,0.f,0.f,0.f};
    #pragma unroll
    for (int ksi = 0; ksi < 8; ksi++){
      union { uint4 v; unsigned short s_[8]; } u;
      u.v = *(const uint4*)(base + ksi*PART);
      #pragma unroll
      for (int j = 0; j < 8; j++) a[j] += bf2f(u.s_[j]);
    }
    float4 lo = {a[0],a[1],a[2],a[3]}, hi = {a[4],a[5],a[6],a[7]};
    *(float4*)(PQsh + s*64 + ch*8)     = lo;
    *(float4*)(PQsh + s*64 + ch*8 + 4) = hi;
  }
  for (int pi = t; pi < 400; pi += 256){
    int r = pi >> 3, ch = pi & 7;
    const unsigned short* base = Cp1 + (size_t)(nsp*50 + r)*8192 + 4096 + och*64 + ch*8;
    float a[8] = {0.f,0.f,0.f,0.f,0.f,0.f,0.f,0.f};
    #pragma unroll
    for (int ksi = 0; ksi < 8; ksi++){
      union { uint4 v; unsigned short s_[8]; } u;
      u.v = *(const uint4*)(base + ksi*PART);
      #pragma unroll
      for (int j = 0; j < 8; j++) a[j] += bf2f(u.s_[j]);
    }
    float4 lo = {a[0],a[1],a[2],a[3]}, hi = {a[4],a[5],a[6],a[7]};
    *(float4*)(Qsh + r*64 + ch*8)     = lo;
    *(float4*)(Qsh + r*64 + ch*8 + 4) = hi;
  }
  __syncthreads();

  const int w = t >> 6, lane = t & 63;
  const int o = och*64 + lane;
  const int jb = w*13;
  const int jn = (w == 3) ? 11 : 13;
  float acc[13];
  #pragma unroll
  for (int i = 0; i < 13; i++) acc[i] = 0.f;
  #pragma unroll 4
  for (int s = 0; s < 200; s++){
    float p = PQsh[s*64 + lane];
    #pragma unroll
    for (int i = 0; i < 13; i++)
      if (i < jn) acc[i] = fmaf(Ssh[s*50 + jb + i], p, acc[i]);
  }
  float bo = b1[o];
  #pragma unroll
  for (int i = 0; i < 13; i++)
    if (i < jn){
      int r = nsp*50 + jb + i;
      float h = acc[i] + Qsh[(jb + i)*64 + lane] + bo;
      h = fmaxf(h, 0.f);
      int kc = o >> 6, wi = o & 63, slot = wi >> 3, rem = wi & 7;
      *(__bf16*)(H1b + (size_t)r*8192 + kc*128 + (((slot ^ (r & 7)) << 4) | (rem*2))) = (__bf16)h;
    }
  int zi = blockIdx.x*256 + t;
  if (zi < 56*512){
    int r = 200 + (zi >> 9), c = zi & 511;
    *(uint4*)(H1b + (size_t)r*8192 + c*16) = (uint4){0,0,0,0};
  }
}

// ---- k_tail: fused reduce32 + h2 + classifier. grid 8 x 512 ------------------
// Block cch owns h2 cols [cch*64, +64): stage R-tile[200][64] (sum 32 partials),
// zt = T + b2 (transposed), accumulate S@R into zt over 16 nsp slices, then MLP.
__global__ __launch_bounds__(512) void k_tail(const unsigned short* __restrict__ Cp2,
    const float* __restrict__ Straw, const float* __restrict__ rcnt,
    const float* __restrict__ b2,
    const float* __restrict__ Wc1, const float* __restrict__ bc1,
    const float* __restrict__ Wc2, const float* __restrict__ bc2,
    const float* __restrict__ Wc3, const float* __restrict__ bc3,
    float* __restrict__ out){
  alignas(16) __shared__ unsigned char LB[113152];
  float* Rsh = (float*)LB;                   // 200*64
  float* zt  = (float*)(LB + 51200);         // 64*201
  float* Ssh = (float*)(LB + 102656);        // 200*13
  float* rcl = (float*)(LB + 113056);        // 13
  float* z1  = (float*)LB;                   // reuse (64*101) after h2 done
  float* z2  = (float*)(LB + 25856);         // 64*51
  const int cch = blockIdx.x;                // 0..7
  const int t = threadIdx.x;
  constexpr size_t PART = (size_t)224*1024;

  // stage R-tile
  for (int pi = t; pi < 1600; pi += 512){
    int s = pi >> 3, ch = pi & 7;
    const unsigned short* base = Cp2 + (size_t)s*1024 + cch*64 + ch*8;
    float a[8] = {0.f,0.f,0.f,0.f,0.f,0.f,0.f,0.f};
    #pragma unroll
    for (int ksi = 0; ksi < 32; ksi++){
      union { uint4 v; unsigned short s_[8]; } u;
      u.v = *(const uint4*)(base + ksi*PART);
      #pragma unroll
      for (int j = 0; j < 8; j++) a[j] += bf2f(u.s_[j]);
    }
    float4 lo = {a[0],a[1],a[2],a[3]}, hi = {a[4],a[5],a[6],a[7]};
    *(float4*)(Rsh + s*64 + ch*8)     = lo;
    *(float4*)(Rsh + s*64 + ch*8 + 4) = hi;
  }
  // zt = T + b2 (transposed write)
  for (int pi = t; pi < 1600; pi += 512){
    int n = pi >> 3, ch = pi & 7;
    const unsigned short* base = Cp2 + (size_t)n*1024 + 512 + cch*64 + ch*8;
    float a[8] = {0.f,0.f,0.f,0.f,0.f,0.f,0.f,0.f};
    #pragma unroll
    for (int ksi = 0; ksi < 32; ksi++){
      union { uint4 v; unsigned short s_[8]; } u;
      u.v = *(const uint4*)(base + ksi*PART);
      #pragma unroll
      for (int j = 0; j < 8; j++) a[j] += bf2f(u.s_[j]);
    }
    #pragma unroll
    for (int j = 0; j < 8; j++)
      zt[(ch*8 + j)*201 + n] = a[j] + b2[cch*64 + ch*8 + j];
  }
  __syncthreads();

  // h2: zt[c][n] += sum_s S[s][n] * R[s][c], over 16 n-slices of 13
  const int c = t & 63, w = t >> 6;
  for (int nsp = 0; nsp < 16; nsp++){
    const int nb0 = nsp * 13;
    if (t < 13) rcl[t] = (nb0 + t < 200) ? rcnt[nb0 + t] : 0.f;
    __syncthreads();
    for (int i = t; i < 200*13; i += 512){
      int s = i / 13, j = i - s*13;
      int g = nb0 + j;
      Ssh[i] = (g < 200) ? Straw[s*200 + g] * rcl[j] : 0.f;
    }
    __syncthreads();
    #pragma unroll
    for (int jj = 0; jj < 2; jj++){
      int j = w + jj*8;
      if (j < 13 && nb0 + j < 200){
        float acc = 0.f;
        #pragma unroll 4
        for (int s = 0; s < 200; s++)
          acc = fmaf(Ssh[s*13 + j], Rsh[s*64 + c], acc);
        zt[c*201 + nb0 + j] += acc;
      }
    }
    __syncthreads();
  }

  // classifier from zt (LDS)
  const int cb = cch * 64;
  {
    const int jb = __builtin_amdgcn_readfirstlane(w*13);
    const int jn = (w == 7) ? 9 : 13;
    float a[13];
    #pragma unroll
    for (int j = 0; j < 13; j++) a[j] = (j < jn) ? bc1[jb + j] : 0.f;
    for (int n = 0; n < 200; n++){
      float v = zt[c*201 + n];
      #pragma unroll
      for (int j = 0; j < 13; j++)
        if (j < jn) a[j] = fmaf(v, Wc1[(jb + j)*200 + n], a[j]);
    }
    __syncthreads();                      // Rsh no longer needed; z1 aliases it
    #pragma unroll
    for (int j = 0; j < 13; j++)
      if (j < jn) z1[c*101 + jb + j] = fmaxf(a[j], 0.f);
  }
  __syncthreads();
  {
    const int jb = __builtin_amdgcn_readfirstlane(w*7);
    const int jn = (w == 7) ? 1 : 7;
    float a[7];
    #pragma unroll
    for (int j = 0; j < 7; j++) a[j] = (j < jn) ? bc2[jb + j] : 0.f;
    for (int n = 0; n < 100; n++){
      float v = z1[c*101 + n];
      #pragma unroll
      for (int j = 0; j < 7; j++)
        if (j < jn) a[j] = fmaf(v, Wc2[(jb + j)*100 + n], a[j]);
    }
    #pragma unroll
    for (int j = 0; j < 7; j++)
      if (j < jn) z2[c*51 + jb + j] = fmaxf(a[j], 0.f);
  }
  __syncthreads();
  if (w < 5){
    const int jb = __builtin_amdgcn_readfirstlane(w*2);
    float a[2] = { bc3[jb], bc3[jb + 1] };
    for (int n = 0; n < 50; n++){
      float v = z2[c*51 + n];
      a[0] = fmaf(v, Wc3[jb*50 + n], a[0]);
      a[1] = fmaf(v, Wc3[(jb + 1)*50 + n], a[1]);
    }
    out[(size_t)(cb + c)*10 + jb]     = a[0];
    out[(size_t)(cb + c)*10 + jb + 1] = a[1];
  }
}

// ---------------- host launch ---------------------------------------------------
extern "C" void kernel_launch(void* const* d_in, const int* in_sizes, int n_in,
                              void* d_out, int out_size, void* d_ws, size_t ws_size,
                              hipStream_t stream){
  (void)n_in; (void)out_size; (void)ws_size;
  const float* x   = (const float*)d_in[0];
  const int*   ei  = (const int*)  d_in[1];
  const float* ea  = (const float*)d_in[2];
  const float* W1l = (const float*)d_in[3];
  const float* W1r = (const float*)d_in[4];
  const float* b1  = (const float*)d_in[5];
  const float* W2l = (const float*)d_in[6];
  const float* W2r = (const float*)d_in[7];
  const float* b2  = (const float*)d_in[8];
  const float* Wc1 = (const float*)d_in[9];
  const float* bc1 = (const float*)d_in[10];
  const float* Wc2 = (const float*)d_in[11];
  const float* bc2 = (const float*)d_in[12];
  const float* Wc3 = (const float*)d_in[13];
  const float* bc3 = (const float*)d_in[14];
  float* out = (float*)d_out;
  char* ws = (char*)d_ws;
  const int E = in_sizes[1] / 2;

  constexpr size_t ST_OFF  = 0;                                   // Straw 160000
  constexpr size_t RC_OFF  = 160000;                              // rcnt 800
  constexpr size_t XB_OFF  = 262144;                              // Xb 8 MiB
  constexpr size_t CP1_OFF = XB_OFF + (size_t)256*16384*2;        // 8 x 224 x 8192 bf16
  constexpr size_t H1B_OFF = CP1_OFF + (size_t)8*224*8192*2;      // 256 x 4096 bf16
  constexpr size_t CP2_OFF = H1B_OFF + (size_t)256*4096*2;        // 32 x 224 x 1024 bf16

  float*          St  = (float*)(ws + ST_OFF);
  float*          rc  = (float*)(ws + RC_OFF);
  unsigned char*  Xb  = (unsigned char*)(ws + XB_OFF);
  unsigned short* Cp1 = (unsigned short*)(ws + CP1_OFF);
  unsigned char*  H1b = (unsigned char*)(ws + H1B_OFF);
  unsigned short* Cp2 = (unsigned short*)(ws + CP2_OFF);

  k_pre<<<dim3(89), dim3(1024), 0, stream>>>(ei, ea, E, St, rc, x, Xb);
  // GEMM1: BN=128, KS=8, NITER=32, NT loads, grid 512 (2 blocks/CU)
  k_gemm<128, 8, 16384, 8192, 32, 256, true><<<dim3(512), dim3(256), 0, stream>>>(Xb, W1l, W1r, Cp1);
  k_h1r<<<dim3(256), dim3(256), 0, stream>>>(Cp1, St, rc, b1, H1b);
  // GEMM2: BN=128, KS=32, NITER=2, grid 256 (1 block/CU)
  k_gemm<128, 32, 4096, 1024, 2, 256, false><<<dim3(256), dim3(256), 0, stream>>>(H1b, W2l, W2r, Cp2);
  k_tail<<<dim3(8), dim3(512), 0, stream>>>(Cp2, St, rc, b2, Wc1, bc1, Wc2, bc2, Wc3, bc3, out);
}

// Round 16
// 382.650 us; speedup vs baseline: 1.3464x; 1.3464x over previous
//
#include <hip/hip_runtime.h>
#include <hip/hip_bf16.h>
#include <cstdint>
#include <cstddef>

typedef __bf16 bf16x8 __attribute__((ext_vector_type(8)));
typedef float  f32x4  __attribute__((ext_vector_type(4)));

typedef const __attribute__((address_space(1))) unsigned int gu32;
typedef __attribute__((address_space(3))) unsigned int lu32;

static __device__ __forceinline__ float bf2f(unsigned short u){
  unsigned v = ((unsigned)u) << 16;
  return __builtin_bit_cast(float, v);
}
static __device__ __forceinline__ unsigned short f2bf_bits(float f){
  __bf16 h = (__bf16)f;
  return __builtin_bit_cast(unsigned short, h);
}

// ---- K_pre: blocks 0..24 scatter edges -> Straw,rcnt; blocks 25..88 xb -------
__global__ __launch_bounds__(1024) void k_pre(const int* __restrict__ ei,
                                              const float* __restrict__ ea,
                                              int E, float* __restrict__ Straw,
                                              float* __restrict__ rcnt,
                                              const float* __restrict__ x,
                                              unsigned char* __restrict__ Xb){
  const int t = threadIdx.x;
  if (blockIdx.x < 25){
    __shared__ float Ssh[8*200];
    __shared__ float csh[200];
    __shared__ int nzsh;
    const int s0 = blockIdx.x * 8;
    if (t == 0) nzsh = 0;
    for (int i = t; i < 1600; i += 1024) Ssh[i] = 0.f;
    if (t < 200) csh[t] = 0.f;
    __syncthreads();
    if (t < 256){ if (ei[2*t + 1] != 0) atomicOr(&nzsh, 1); }
    __syncthreads();
    const int is64 = (nzsh == 0);
    const bool do_cnt = (blockIdx.x == 0);
    for (int e = t; e < E; e += 1024){
      int s, d;
      if (is64){ s = ei[2*e]; d = ei[2*(E+e)]; }
      else     { s = ei[e];   d = ei[E+e];     }
      if ((unsigned)s < 200u && (unsigned)d < 200u){
        if (do_cnt) atomicAdd(&csh[d], 1.f);
        unsigned ls = (unsigned)(s - s0);
        if (ls < 8u) atomicAdd(&Ssh[ls*200 + d], ea[e]);
      }
    }
    __syncthreads();
    for (int i = t; i < 1600; i += 1024)
      Straw[(size_t)s0*200 + i] = Ssh[i];
    if (do_cnt && t < 200) rcnt[t] = 1.f / fmaxf(csh[t], 1.f);
  } else {
    int idx0 = (blockIdx.x - 25)*1024 + t;
    for (int idx = idx0; idx < 256*2048; idx += 64*1024){
      int r  = idx >> 11;
      int sl = idx & 2047;
      int kc = sl >> 3, s = sl & 7;
      float4 v0 = {0.f,0.f,0.f,0.f}, v1 = {0.f,0.f,0.f,0.f};
      if (r < 200){
        const float* p = x + (size_t)r*16384 + kc*64 + s*8;
        v0 = *(const float4*)p;
        v1 = *(const float4*)(p + 4);
      }
      union { uint4 u; __bf16 h[8]; } pk;
      pk.h[0]=(__bf16)v0.x; pk.h[1]=(__bf16)v0.y; pk.h[2]=(__bf16)v0.z; pk.h[3]=(__bf16)v0.w;
      pk.h[4]=(__bf16)v1.x; pk.h[5]=(__bf16)v1.y; pk.h[6]=(__bf16)v1.z; pk.h[7]=(__bf16)v1.w;
      *(uint4*)(Xb + (size_t)r*32768 + kc*128 + ((s ^ (r & 7)) << 4)) = pk.u;
    }
  }
}

// ---------------- GEMM: Cpart[ks][224][NOUT] = A(256pad x K) * [Wl;Wr]^T -------
template<int BN, int KSPLIT, int KDIM, int NOUT, int NITER, int NTHREADS, bool NT>
__global__ __launch_bounds__(NTHREADS, 1024/NTHREADS/2)
void k_gemm(const unsigned char* __restrict__ Asrc,
            const float* __restrict__ Wl,
            const float* __restrict__ Wr,
            unsigned short* __restrict__ Cpart){
  constexpr int ROWB = KDIM * 2;
  constexpr int NT2  = (NOUT/2) / BN;
  constexpr int NS   = 2;
  constexpr int NB   = 8;
  constexpr int AJ   = 32768 / (NTHREADS*16);
  constexpr int VMC  = 8 + AJ;
  static_assert(BN/32 == NTHREADS/64, "wave owns 32 cols");
  static_assert(VMC == 12 || VMC == 16, "vmcnt literal");
  __shared__ unsigned char Lds[2][256*128];

  const int tid  = threadIdx.x;
  const int lane = tid & 63, wid = tid >> 6;
  const int l15  = lane & 15, lk = lane >> 4;
  const int bid  = blockIdx.x;
  const int ks    = bid & (KSPLIT - 1);
  const int ntile = bid / KSPLIT;
  const float* W = (ntile < NT2) ? (Wl + (size_t)ntile*BN*KDIM)
                                 : (Wr + (size_t)(ntile - NT2)*BN*KDIM);
  const int kc0   = ks * NITER;
  const int phase = ntile & (NITER - 1);
  auto kcAt = [&](int i){ return kc0 + ((i + phase) & (NITER - 1)); };

  const float* WB = W + (size_t)(wid*32 + l15)*KDIM + lk*8;
  f32x4 b0[NB], b1[NB];

  auto issueB = [&](f32x4 (&b)[NB], int kc){
    const float* p = WB + (size_t)kc*64;
    #pragma unroll
    for (int ns = 0; ns < NS; ns++)
      #pragma unroll
      for (int kst = 0; kst < 2; kst++){
        const f32x4* q = (const f32x4*)(p + (size_t)ns*16*KDIM + kst*32);
        if constexpr (NT){
          b[(ns*2+kst)*2 + 0] = __builtin_nontemporal_load(q);
          b[(ns*2+kst)*2 + 1] = __builtin_nontemporal_load(q + 1);
        } else {
          b[(ns*2+kst)*2 + 0] = *q;
          b[(ns*2+kst)*2 + 1] = *(q + 1);
        }
      }
    __builtin_amdgcn_sched_barrier(0);
  };

  const unsigned char* AG = Asrc + (size_t)(tid >> 3)*ROWB + (tid & 7)*16;
  auto issueA = [&](unsigned char* buf, int kc){
    const unsigned char* g = AG + (size_t)kc*128;
    #pragma unroll
    for (int j = 0; j < AJ; j++){
      __builtin_amdgcn_global_load_lds(
          (gu32*)(g + (size_t)j*(NTHREADS/8)*ROWB),
          (lu32*)(buf + j*(NTHREADS*16) + wid*1024),
          16, 0, 0);
    }
    __builtin_amdgcn_sched_barrier(0);
  };

  bf16x8 frag[NS*2];
  auto cvtB = [&](const f32x4 (&b)[NB]){
    #pragma unroll
    for (int f = 0; f < NS*2; f++){
      f32x4 lo = b[f*2], hi = b[f*2+1];
      bf16x8 v;
      v[0]=(__bf16)lo[0]; v[1]=(__bf16)lo[1]; v[2]=(__bf16)lo[2]; v[3]=(__bf16)lo[3];
      v[4]=(__bf16)hi[0]; v[5]=(__bf16)hi[1]; v[6]=(__bf16)hi[2]; v[7]=(__bf16)hi[3];
      frag[f] = v;
    }
  };

  f32x4 acc[14][NS];
  #pragma unroll
  for (int mt = 0; mt < 14; mt++)
    #pragma unroll
    for (int ns = 0; ns < NS; ns++)
      acc[mt][ns] = (f32x4){0.f,0.f,0.f,0.f};

  auto compute = [&](const unsigned char* buf){
    #pragma unroll
    for (int kst = 0; kst < 2; kst++){
      const int sx = (((kst*4 + lk) ^ (l15 & 7)) << 4);
      #pragma unroll
      for (int mt = 0; mt < 14; mt++){
        bf16x8 af = *(const bf16x8*)(buf + (mt*16 + l15)*128 + sx);
        #pragma unroll
        for (int ns = 0; ns < NS; ns++)
          acc[mt][ns] = __builtin_amdgcn_mfma_f32_16x16x32_bf16(af, frag[ns*2+kst], acc[mt][ns], 0, 0, 0);
      }
    }
  };

  auto STAGE = [&](f32x4 (&bc)[NB], unsigned char* Lc, int i){
    if (i + 1 < NITER){
      if constexpr (VMC == 12) asm volatile("s_waitcnt vmcnt(12) lgkmcnt(0)" ::: "memory");
      else                     asm volatile("s_waitcnt vmcnt(16) lgkmcnt(0)" ::: "memory");
    } else {
      asm volatile("s_waitcnt vmcnt(0) lgkmcnt(0)" ::: "memory");
    }
    __builtin_amdgcn_s_barrier();
    __builtin_amdgcn_sched_barrier(0);
    cvtB(bc);
    if (i + 2 < NITER) issueB(bc, kcAt(i + 2));
    __builtin_amdgcn_sched_barrier(0);
    compute(Lc);
    __builtin_amdgcn_s_barrier();
    __builtin_amdgcn_sched_barrier(0);
    if (i + 2 < NITER) issueA(Lc, kcAt(i + 2));
  };

  issueB(b0, kcAt(0)); issueA(Lds[0], kcAt(0));
  issueB(b1, kcAt(1)); issueA(Lds[1], kcAt(1));

  for (int i = 0; i < NITER; i += 2){
    STAGE(b0, Lds[0], i);
    STAGE(b1, Lds[1], i + 1);
  }

  const int rbase = ks * 224;
  const int cbase = ntile*BN + wid*32;
  #pragma unroll
  for (int mt = 0; mt < 14; mt++)
    #pragma unroll
    for (int ns = 0; ns < NS; ns++)
      #pragma unroll
      for (int j = 0; j < 4; j++){
        int row = mt*16 + lk*4 + j;
        int col = cbase + ns*16 + l15;
        Cpart[(size_t)(rbase + row)*NOUT + col] = f2bf_bits(acc[mt][ns][j]);
      }
}

// ---- k_h1r: fused reduce8 + h1 -> H1b (swizzled bf16) + zero-tail -------------
__global__ __launch_bounds__(256) void k_h1r(const unsigned short* __restrict__ Cp1,
                                             const float* __restrict__ Straw,
                                             const float* __restrict__ rcnt,
                                             const float* __restrict__ b1,
                                             unsigned char* __restrict__ H1b){
  __shared__ float PQsh[200*64];
  __shared__ float Qsh[50*64];
  __shared__ float Ssh[200*50];
  __shared__ float rcl[50];
  const int och = blockIdx.x >> 2, nsp = blockIdx.x & 3;
  const int t = threadIdx.x;
  constexpr size_t PART = (size_t)224*8192;

  if (t < 50) rcl[t] = rcnt[nsp*50 + t];
  __syncthreads();
  for (int i = t; i < 200*50; i += 256){
    int s = i / 50, j = i - s*50;
    Ssh[i] = Straw[s*200 + nsp*50 + j] * rcl[j];
  }
  for (int pi = t; pi < 1600; pi += 256){
    int s = pi >> 3, ch = pi & 7;
    const unsigned short* base = Cp1 + (size_t)s*8192 + och*64 + ch*8;
    float a[8] = {0.f,0.f,0.f,0.f,0.f,0.f,0.f,0.f};
    #pragma unroll
    for (int ksi = 0; ksi < 8; ksi++){
      union { uint4 v; unsigned short s_[8]; } u;
      u.v = *(const uint4*)(base + ksi*PART);
      #pragma unroll
      for (int j = 0; j < 8; j++) a[j] += bf2f(u.s_[j]);
    }
    float4 lo = {a[0],a[1],a[2],a[3]}, hi = {a[4],a[5],a[6],a[7]};
    *(float4*)(PQsh + s*64 + ch*8)     = lo;
    *(float4*)(PQsh + s*64 + ch*8 + 4) = hi;
  }
  for (int pi = t; pi < 400; pi += 256){
    int r = pi >> 3, ch = pi & 7;
    const unsigned short* base = Cp1 + (size_t)(nsp*50 + r)*8192 + 4096 + och*64 + ch*8;
    float a[8] = {0.f,0.f,0.f,0.f,0.f,0.f,0.f,0.f};
    #pragma unroll
    for (int ksi = 0; ksi < 8; ksi++){
      union { uint4 v; unsigned short s_[8]; } u;
      u.v = *(const uint4*)(base + ksi*PART);
      #pragma unroll
      for (int j = 0; j < 8; j++) a[j] += bf2f(u.s_[j]);
    }
    float4 lo = {a[0],a[1],a[2],a[3]}, hi = {a[4],a[5],a[6],a[7]};
    *(float4*)(Qsh + r*64 + ch*8)     = lo;
    *(float4*)(Qsh + r*64 + ch*8 + 4) = hi;
  }
  __syncthreads();

  const int w = t >> 6, lane = t & 63;
  const int o = och*64 + lane;
  const int jb = w*13;
  const int jn = (w == 3) ? 11 : 13;
  float acc[13];
  #pragma unroll
  for (int i = 0; i < 13; i++) acc[i] = 0.f;
  #pragma unroll 4
  for (int s = 0; s < 200; s++){
    float p = PQsh[s*64 + lane];
    #pragma unroll
    for (int i = 0; i < 13; i++)
      if (i < jn) acc[i] = fmaf(Ssh[s*50 + jb + i], p, acc[i]);
  }
  float bo = b1[o];
  #pragma unroll
  for (int i = 0; i < 13; i++)
    if (i < jn){
      int r = nsp*50 + jb + i;
      float h = acc[i] + Qsh[(jb + i)*64 + lane] + bo;
      h = fmaxf(h, 0.f);
      int kc = o >> 6, wi = o & 63, slot = wi >> 3, rem = wi & 7;
      *(__bf16*)(H1b + (size_t)r*8192 + kc*128 + (((slot ^ (r & 7)) << 4) | (rem*2))) = (__bf16)h;
    }
  int zi = blockIdx.x*256 + t;
  if (zi < 56*512){
    int r = 200 + (zi >> 9), c = zi & 511;
    *(uint4*)(H1b + (size_t)r*8192 + c*16) = (uint4){0,0,0,0};
  }
}

// ---- k_h2r: fused reduce32 + h2. Block (cch 8 x nsp 16): stage R-tile[200][64]
// and T-tile[13][64] from 32 Cp2 partials, then h2 = S@R + T + b2. -------------
__global__ __launch_bounds__(256) void k_h2r(const unsigned short* __restrict__ Cp2,
                                             const float* __restrict__ Straw,
                                             const float* __restrict__ rcnt,
                                             const float* __restrict__ b2,
                                             float* __restrict__ h2){
  __shared__ float Rsh[200*64];
  __shared__ float Tsh[13*64];
  __shared__ float Ssh[200*13];
  __shared__ float rcl[13];
  const int cch = blockIdx.x >> 4, nsp = blockIdx.x & 15;
  const int nb0 = nsp * 13;
  const int t = threadIdx.x;
  constexpr size_t PART = (size_t)224*1024;

  if (t < 13) rcl[t] = (nb0 + t < 200) ? rcnt[nb0 + t] : 0.f;
  __syncthreads();
  for (int i = t; i < 200*13; i += 256){
    int s = i / 13, j = i - s*13;
    int g = nb0 + j;
    Ssh[i] = (g < 200) ? Straw[s*200 + g] * rcl[j] : 0.f;
  }
  for (int pi = t; pi < 1600; pi += 256){
    int s = pi >> 3, ch = pi & 7;
    const unsigned short* base = Cp2 + (size_t)s*1024 + cch*64 + ch*8;
    float a[8] = {0.f,0.f,0.f,0.f,0.f,0.f,0.f,0.f};
    #pragma unroll
    for (int ksi = 0; ksi < 32; ksi++){
      union { uint4 v; unsigned short s_[8]; } u;
      u.v = *(const uint4*)(base + ksi*PART);
      #pragma unroll
      for (int j = 0; j < 8; j++) a[j] += bf2f(u.s_[j]);
    }
    float4 lo = {a[0],a[1],a[2],a[3]}, hi = {a[4],a[5],a[6],a[7]};
    *(float4*)(Rsh + s*64 + ch*8)     = lo;
    *(float4*)(Rsh + s*64 + ch*8 + 4) = hi;
  }
  for (int pi = t; pi < 104; pi += 256){
    int r = pi >> 3, ch = pi & 7;
    int n = nb0 + r;
    float a[8] = {0.f,0.f,0.f,0.f,0.f,0.f,0.f,0.f};
    if (n < 200){
      const unsigned short* base = Cp2 + (size_t)n*1024 + 512 + cch*64 + ch*8;
      #pragma unroll
      for (int ksi = 0; ksi < 32; ksi++){
        union { uint4 v; unsigned short s_[8]; } u;
        u.v = *(const uint4*)(base + ksi*PART);
        #pragma unroll
        for (int j = 0; j < 8; j++) a[j] += bf2f(u.s_[j]);
      }
    }
    float4 lo = {a[0],a[1],a[2],a[3]}, hi = {a[4],a[5],a[6],a[7]};
    *(float4*)(Tsh + r*64 + ch*8)     = lo;
    *(float4*)(Tsh + r*64 + ch*8 + 4) = hi;
  }
  __syncthreads();

  const int w = t >> 6, lane = t & 63;
  const int c = cch*64 + lane;
  float acc[4] = {0.f, 0.f, 0.f, 0.f};
  #pragma unroll 4
  for (int s = 0; s < 200; s++){
    float r = Rsh[s*64 + lane];
    #pragma unroll
    for (int ii = 0; ii < 4; ii++){
      int j = w*4 + ii;
      if (j < 13 && nb0 + j < 200)
        acc[ii] = fmaf(Ssh[s*13 + j], r, acc[ii]);
    }
  }
  float bc = b2[c];
  #pragma unroll
  for (int ii = 0; ii < 4; ii++){
    int j = w*4 + ii;
    if (j < 13 && nb0 + j < 200){
      int n = nb0 + j;
      h2[(size_t)n*512 + c] = acc[ii] + Tsh[j*64 + lane] + bc;
    }
  }
}

// ---------------- classifier: out[512,10] = mlp(h2^T) --------------------------
__global__ __launch_bounds__(512) void k_cls(const float* __restrict__ h2,
    const float* __restrict__ Wc1, const float* __restrict__ bc1,
    const float* __restrict__ Wc2, const float* __restrict__ bc2,
    const float* __restrict__ Wc3, const float* __restrict__ bc3,
    float* __restrict__ out){
  __shared__ float zt[64*201];
  __shared__ float z1[64*101];
  __shared__ float z2[64*51];
  const int cb = blockIdx.x * 64;
  const int t = threadIdx.x;
  for (int idx = t; idx < 64*200; idx += 512){
    int n = idx >> 6, cl = idx & 63;
    zt[cl*201 + n] = h2[(size_t)n*512 + cb + cl];
  }
  __syncthreads();
  const int w = t >> 6, c = t & 63;
  {
    const int jb = __builtin_amdgcn_readfirstlane(w*13);
    const int jn = (w == 7) ? 9 : 13;
    float a[13];
    #pragma unroll
    for (int j = 0; j < 13; j++) a[j] = (j < jn) ? bc1[jb + j] : 0.f;
    for (int n = 0; n < 200; n++){
      float v = zt[c*201 + n];
      #pragma unroll
      for (int j = 0; j < 13; j++)
        if (j < jn) a[j] = fmaf(v, Wc1[(jb + j)*200 + n], a[j]);
    }
    #pragma unroll
    for (int j = 0; j < 13; j++)
      if (j < jn) z1[c*101 + jb + j] = fmaxf(a[j], 0.f);
  }
  __syncthreads();
  {
    const int jb = __builtin_amdgcn_readfirstlane(w*7);
    const int jn = (w == 7) ? 1 : 7;
    float a[7];
    #pragma unroll
    for (int j = 0; j < 7; j++) a[j] = (j < jn) ? bc2[jb + j] : 0.f;
    for (int n = 0; n < 100; n++){
      float v = z1[c*101 + n];
      #pragma unroll
      for (int j = 0; j < 7; j++)
        if (j < jn) a[j] = fmaf(v, Wc2[(jb + j)*100 + n], a[j]);
    }
    #pragma unroll
    for (int j = 0; j < 7; j++)
      if (j < jn) z2[c*51 + jb + j] = fmaxf(a[j], 0.f);
  }
  __syncthreads();
  if (w < 5){
    const int jb = __builtin_amdgcn_readfirstlane(w*2);
    float a[2] = { bc3[jb], bc3[jb + 1] };
    for (int n = 0; n < 50; n++){
      float v = z2[c*51 + n];
      a[0] = fmaf(v, Wc3[jb*50 + n], a[0]);
      a[1] = fmaf(v, Wc3[(jb + 1)*50 + n], a[1]);
    }
    out[(size_t)(cb + c)*10 + jb]     = a[0];
    out[(size_t)(cb + c)*10 + jb + 1] = a[1];
  }
}

// ---------------- host launch ---------------------------------------------------
extern "C" void kernel_launch(void* const* d_in, const int* in_sizes, int n_in,
                              void* d_out, int out_size, void* d_ws, size_t ws_size,
                              hipStream_t stream){
  (void)n_in; (void)out_size; (void)ws_size;
  const float* x   = (const float*)d_in[0];
  const int*   ei  = (const int*)  d_in[1];
  const float* ea  = (const float*)d_in[2];
  const float* W1l = (const float*)d_in[3];
  const float* W1r = (const float*)d_in[4];
  const float* b1  = (const float*)d_in[5];
  const float* W2l = (const float*)d_in[6];
  const float* W2r = (const float*)d_in[7];
  const float* b2  = (const float*)d_in[8];
  const float* Wc1 = (const float*)d_in[9];
  const float* bc1 = (const float*)d_in[10];
  const float* Wc2 = (const float*)d_in[11];
  const float* bc2 = (const float*)d_in[12];
  const float* Wc3 = (const float*)d_in[13];
  const float* bc3 = (const float*)d_in[14];
  float* out = (float*)d_out;
  char* ws = (char*)d_ws;
  const int E = in_sizes[1] / 2;

  constexpr size_t ST_OFF  = 0;                                   // Straw 160000
  constexpr size_t RC_OFF  = 160000;                              // rcnt 800
  constexpr size_t XB_OFF  = 262144;                              // Xb 8 MiB
  constexpr size_t CP1_OFF = XB_OFF + (size_t)256*16384*2;        // 8 x 224 x 8192 bf16
  constexpr size_t H1B_OFF = CP1_OFF + (size_t)8*224*8192*2;      // 256 x 4096 bf16
  constexpr size_t CP2_OFF = H1B_OFF + (size_t)256*4096*2;        // 32 x 224 x 1024 bf16
  constexpr size_t H2_OFF  = CP2_OFF + (size_t)32*224*1024*2;     // 200 x 512 f32

  float*          St  = (float*)(ws + ST_OFF);
  float*          rc  = (float*)(ws + RC_OFF);
  unsigned char*  Xb  = (unsigned char*)(ws + XB_OFF);
  unsigned short* Cp1 = (unsigned short*)(ws + CP1_OFF);
  unsigned char*  H1b = (unsigned char*)(ws + H1B_OFF);
  unsigned short* Cp2 = (unsigned short*)(ws + CP2_OFF);
  float*          h2  = (float*)(ws + H2_OFF);

  k_pre<<<dim3(89), dim3(1024), 0, stream>>>(ei, ea, E, St, rc, x, Xb);
  // GEMM1: BN=128, KS=8, NITER=32, NT loads, grid 512 (2 blocks/CU)
  k_gemm<128, 8, 16384, 8192, 32, 256, true><<<dim3(512), dim3(256), 0, stream>>>(Xb, W1l, W1r, Cp1);
  k_h1r<<<dim3(256), dim3(256), 0, stream>>>(Cp1, St, rc, b1, H1b);
  // GEMM2: BN=128, KS=32, NITER=2, grid 256 (1 block/CU)
  k_gemm<128, 32, 4096, 1024, 2, 256, false><<<dim3(256), dim3(256), 0, stream>>>(H1b, W2l, W2r, Cp2);
  k_h2r<<<dim3(128), dim3(256), 0, stream>>>(Cp2, St, rc, b2, h2);
  k_cls<<<dim3(8), dim3(512), 0, stream>>>(h2, Wc1, bc1, Wc2, bc2, Wc3, bc3, out);
}

// Round 17
// 287.008 us; speedup vs baseline: 1.7951x; 1.3332x over previous
//
#include <hip/hip_runtime.h>
#include <hip/hip_bf16.h>
#include <cstdint>
#include <cstddef>

typedef __bf16 bf16x8 __attribute__((ext_vector_type(8)));
typedef float  f32x4  __attribute__((ext_vector_type(4)));

typedef const __attribute__((address_space(1))) unsigned int gu32;
typedef __attribute__((address_space(3))) unsigned int lu32;

static __device__ __forceinline__ float bf2f(unsigned short u){
  unsigned v = ((unsigned)u) << 16;
  return __builtin_bit_cast(float, v);
}
static __device__ __forceinline__ unsigned short f2bf_bits(float f){
  __bf16 h = (__bf16)f;
  return __builtin_bit_cast(unsigned short, h);
}

// ---- K_pre: blocks 0..24 scatter edges -> Straw, rcnt, G = S~ @ Wc1^T;
//      blocks 25..88: xb (x f32 -> Xb bf16 swizzled). --------------------------
__global__ __launch_bounds__(1024) void k_pre(const int* __restrict__ ei,
                                              const float* __restrict__ ea,
                                              int E, float* __restrict__ Straw,
                                              float* __restrict__ rcnt,
                                              const float* __restrict__ Wc1,
                                              float* __restrict__ Gm,
                                              const float* __restrict__ x,
                                              unsigned char* __restrict__ Xb){
  const int t = threadIdx.x;
  if (blockIdx.x < 25){
    __shared__ float Ssh[8*200];
    __shared__ float csh[200];
    __shared__ int nzsh;
    const int s0 = blockIdx.x * 8;
    if (t == 0) nzsh = 0;
    for (int i = t; i < 1600; i += 1024) Ssh[i] = 0.f;
    if (t < 200) csh[t] = 0.f;
    __syncthreads();
    if (t < 256){ if (ei[2*t + 1] != 0) atomicOr(&nzsh, 1); }
    __syncthreads();
    const int is64 = (nzsh == 0);
    for (int e = t; e < E; e += 1024){
      int s, d;
      if (is64){ s = ei[2*e]; d = ei[2*(E+e)]; }
      else     { s = ei[e];   d = ei[E+e];     }
      if ((unsigned)s < 200u && (unsigned)d < 200u){
        atomicAdd(&csh[d], 1.f);                 // every block: local count copy
        unsigned ls = (unsigned)(s - s0);
        if (ls < 8u) atomicAdd(&Ssh[ls*200 + d], ea[e]);
      }
    }
    __syncthreads();
    for (int i = t; i < 1600; i += 1024)
      Straw[(size_t)s0*200 + i] = Ssh[i];
    if (t < 200) csh[t] = 1.f / fmaxf(csh[t], 1.f);   // csh := rcnt
    __syncthreads();
    if (blockIdx.x == 0 && t < 200) rcnt[t] = csh[t];
    // G[s0+ls][j] = sum_n Ssh[ls][n] * rcnt[n] * Wc1[j][n]
    for (int i = t; i < 800; i += 1024){
      int ls = i / 100, j = i - (i/100)*100;
      float acc = 0.f;
      #pragma unroll 4
      for (int n = 0; n < 200; n++)
        acc += Ssh[ls*200 + n] * csh[n] * Wc1[j*200 + n];
      Gm[(size_t)(s0 + ls)*100 + j] = acc;
    }
  } else {
    int idx0 = (blockIdx.x - 25)*1024 + t;
    for (int idx = idx0; idx < 256*2048; idx += 64*1024){
      int r  = idx >> 11;
      int sl = idx & 2047;
      int kc = sl >> 3, s = sl & 7;
      float4 v0 = {0.f,0.f,0.f,0.f}, v1 = {0.f,0.f,0.f,0.f};
      if (r < 200){
        const float* p = x + (size_t)r*16384 + kc*64 + s*8;
        v0 = *(const float4*)p;
        v1 = *(const float4*)(p + 4);
      }
      union { uint4 u; __bf16 h[8]; } pk;
      pk.h[0]=(__bf16)v0.x; pk.h[1]=(__bf16)v0.y; pk.h[2]=(__bf16)v0.z; pk.h[3]=(__bf16)v0.w;
      pk.h[4]=(__bf16)v1.x; pk.h[5]=(__bf16)v1.y; pk.h[6]=(__bf16)v1.z; pk.h[7]=(__bf16)v1.w;
      *(uint4*)(Xb + (size_t)r*32768 + kc*128 + ((s ^ (r & 7)) << 4)) = pk.u;
    }
  }
}

// ---------------- GEMM: Cpart[ks][224][NOUT] = A(256pad x K) * [Wl;Wr]^T -------
template<int BN, int KSPLIT, int KDIM, int NOUT, int NITER, int NTHREADS, bool NT>
__global__ __launch_bounds__(NTHREADS, 1024/NTHREADS/2)
void k_gemm(const unsigned char* __restrict__ Asrc,
            const float* __restrict__ Wl,
            const float* __restrict__ Wr,
            unsigned short* __restrict__ Cpart){
  constexpr int ROWB = KDIM * 2;
  constexpr int NT2  = (NOUT/2) / BN;
  constexpr int NS   = 2;
  constexpr int NB   = 8;
  constexpr int AJ   = 32768 / (NTHREADS*16);
  constexpr int VMC  = 8 + AJ;
  static_assert(BN/32 == NTHREADS/64, "wave owns 32 cols");
  static_assert(VMC == 12 || VMC == 16, "vmcnt literal");
  __shared__ unsigned char Lds[2][256*128];

  const int tid  = threadIdx.x;
  const int lane = tid & 63, wid = tid >> 6;
  const int l15  = lane & 15, lk = lane >> 4;
  const int bid  = blockIdx.x;
  const int ks    = bid & (KSPLIT - 1);
  const int ntile = bid / KSPLIT;
  const float* W = (ntile < NT2) ? (Wl + (size_t)ntile*BN*KDIM)
                                 : (Wr + (size_t)(ntile - NT2)*BN*KDIM);
  const int kc0   = ks * NITER;
  const int phase = ntile & (NITER - 1);
  auto kcAt = [&](int i){ return kc0 + ((i + phase) & (NITER - 1)); };

  const float* WB = W + (size_t)(wid*32 + l15)*KDIM + lk*8;
  f32x4 b0[NB], b1[NB];

  auto issueB = [&](f32x4 (&b)[NB], int kc){
    const float* p = WB + (size_t)kc*64;
    #pragma unroll
    for (int ns = 0; ns < NS; ns++)
      #pragma unroll
      for (int kst = 0; kst < 2; kst++){
        const f32x4* q = (const f32x4*)(p + (size_t)ns*16*KDIM + kst*32);
        if constexpr (NT){
          b[(ns*2+kst)*2 + 0] = __builtin_nontemporal_load(q);
          b[(ns*2+kst)*2 + 1] = __builtin_nontemporal_load(q + 1);
        } else {
          b[(ns*2+kst)*2 + 0] = *q;
          b[(ns*2+kst)*2 + 1] = *(q + 1);
        }
      }
    __builtin_amdgcn_sched_barrier(0);
  };

  const unsigned char* AG = Asrc + (size_t)(tid >> 3)*ROWB + (tid & 7)*16;
  auto issueA = [&](unsigned char* buf, int kc){
    const unsigned char* g = AG + (size_t)kc*128;
    #pragma unroll
    for (int j = 0; j < AJ; j++){
      __builtin_amdgcn_global_load_lds(
          (gu32*)(g + (size_t)j*(NTHREADS/8)*ROWB),
          (lu32*)(buf + j*(NTHREADS*16) + wid*1024),
          16, 0, 0);
    }
    __builtin_amdgcn_sched_barrier(0);
  };

  bf16x8 frag[NS*2];
  auto cvtB = [&](const f32x4 (&b)[NB]){
    #pragma unroll
    for (int f = 0; f < NS*2; f++){
      f32x4 lo = b[f*2], hi = b[f*2+1];
      bf16x8 v;
      v[0]=(__bf16)lo[0]; v[1]=(__bf16)lo[1]; v[2]=(__bf16)lo[2]; v[3]=(__bf16)lo[3];
      v[4]=(__bf16)hi[0]; v[5]=(__bf16)hi[1]; v[6]=(__bf16)hi[2]; v[7]=(__bf16)hi[3];
      frag[f] = v;
    }
  };

  f32x4 acc[14][NS];
  #pragma unroll
  for (int mt = 0; mt < 14; mt++)
    #pragma unroll
    for (int ns = 0; ns < NS; ns++)
      acc[mt][ns] = (f32x4){0.f,0.f,0.f,0.f};

  auto compute = [&](const unsigned char* buf){
    #pragma unroll
    for (int kst = 0; kst < 2; kst++){
      const int sx = (((kst*4 + lk) ^ (l15 & 7)) << 4);
      #pragma unroll
      for (int mt = 0; mt < 14; mt++){
        bf16x8 af = *(const bf16x8*)(buf + (mt*16 + l15)*128 + sx);
        #pragma unroll
        for (int ns = 0; ns < NS; ns++)
          acc[mt][ns] = __builtin_amdgcn_mfma_f32_16x16x32_bf16(af, frag[ns*2+kst], acc[mt][ns], 0, 0, 0);
      }
    }
  };

  auto STAGE = [&](f32x4 (&bc)[NB], unsigned char* Lc, int i){
    if (i + 1 < NITER){
      if constexpr (VMC == 12) asm volatile("s_waitcnt vmcnt(12) lgkmcnt(0)" ::: "memory");
      else                     asm volatile("s_waitcnt vmcnt(16) lgkmcnt(0)" ::: "memory");
    } else {
      asm volatile("s_waitcnt vmcnt(0) lgkmcnt(0)" ::: "memory");
    }
    __builtin_amdgcn_s_barrier();
    __builtin_amdgcn_sched_barrier(0);
    cvtB(bc);
    if (i + 2 < NITER) issueB(bc, kcAt(i + 2));
    __builtin_amdgcn_sched_barrier(0);
    compute(Lc);
    __builtin_amdgcn_s_barrier();
    __builtin_amdgcn_sched_barrier(0);
    if (i + 2 < NITER) issueA(Lc, kcAt(i + 2));
  };

  issueB(b0, kcAt(0)); issueA(Lds[0], kcAt(0));
  issueB(b1, kcAt(1)); issueA(Lds[1], kcAt(1));

  for (int i = 0; i < NITER; i += 2){
    STAGE(b0, Lds[0], i);
    STAGE(b1, Lds[1], i + 1);
  }

  const int rbase = ks * 224;
  const int cbase = ntile*BN + wid*32;
  #pragma unroll
  for (int mt = 0; mt < 14; mt++)
    #pragma unroll
    for (int ns = 0; ns < NS; ns++)
      #pragma unroll
      for (int j = 0; j < 4; j++){
        int row = mt*16 + lk*4 + j;
        int col = cbase + ns*16 + l15;
        Cpart[(size_t)(rbase + row)*NOUT + col] = f2bf_bits(acc[mt][ns][j]);
      }
}

// ---- k_h1r: fused reduce8 + h1 -> H1b (swizzled bf16) + zero-tail -------------
__global__ __launch_bounds__(256) void k_h1r(const unsigned short* __restrict__ Cp1,
                                             const float* __restrict__ Straw,
                                             const float* __restrict__ rcnt,
                                             const float* __restrict__ b1,
                                             unsigned char* __restrict__ H1b){
  __shared__ float PQsh[200*64];
  __shared__ float Qsh[50*64];
  __shared__ float Ssh[200*50];
  __shared__ float rcl[50];
  const int och = blockIdx.x >> 2, nsp = blockIdx.x & 3;
  const int t = threadIdx.x;
  constexpr size_t PART = (size_t)224*8192;

  if (t < 50) rcl[t] = rcnt[nsp*50 + t];
  __syncthreads();
  for (int i = t; i < 200*50; i += 256){
    int s = i / 50, j = i - s*50;
    Ssh[i] = Straw[s*200 + nsp*50 + j] * rcl[j];
  }
  for (int pi = t; pi < 1600; pi += 256){
    int s = pi >> 3, ch = pi & 7;
    const unsigned short* base = Cp1 + (size_t)s*8192 + och*64 + ch*8;
    float a[8] = {0.f,0.f,0.f,0.f,0.f,0.f,0.f,0.f};
    #pragma unroll
    for (int ksi = 0; ksi < 8; ksi++){
      union { uint4 v; unsigned short s_[8]; } u;
      u.v = *(const uint4*)(base + ksi*PART);
      #pragma unroll
      for (int j = 0; j < 8; j++) a[j] += bf2f(u.s_[j]);
    }
    float4 lo = {a[0],a[1],a[2],a[3]}, hi = {a[4],a[5],a[6],a[7]};
    *(float4*)(PQsh + s*64 + ch*8)     = lo;
    *(float4*)(PQsh + s*64 + ch*8 + 4) = hi;
  }
  for (int pi = t; pi < 400; pi += 256){
    int r = pi >> 3, ch = pi & 7;
    const unsigned short* base = Cp1 + (size_t)(nsp*50 + r)*8192 + 4096 + och*64 + ch*8;
    float a[8] = {0.f,0.f,0.f,0.f,0.f,0.f,0.f,0.f};
    #pragma unroll
    for (int ksi = 0; ksi < 8; ksi++){
      union { uint4 v; unsigned short s_[8]; } u;
      u.v = *(const uint4*)(base + ksi*PART);
      #pragma unroll
      for (int j = 0; j < 8; j++) a[j] += bf2f(u.s_[j]);
    }
    float4 lo = {a[0],a[1],a[2],a[3]}, hi = {a[4],a[5],a[6],a[7]};
    *(float4*)(Qsh + r*64 + ch*8)     = lo;
    *(float4*)(Qsh + r*64 + ch*8 + 4) = hi;
  }
  __syncthreads();

  const int w = t >> 6, lane = t & 63;
  const int o = och*64 + lane;
  const int jb = w*13;
  const int jn = (w == 3) ? 11 : 13;
  float acc[13];
  #pragma unroll
  for (int i = 0; i < 13; i++) acc[i] = 0.f;
  #pragma unroll 4
  for (int s = 0; s < 200; s++){
    float p = PQsh[s*64 + lane];
    #pragma unroll
    for (int i = 0; i < 13; i++)
      if (i < jn) acc[i] = fmaf(Ssh[s*50 + jb + i], p, acc[i]);
  }
  float bo = b1[o];
  #pragma unroll
  for (int i = 0; i < 13; i++)
    if (i < jn){
      int r = nsp*50 + jb + i;
      float h = acc[i] + Qsh[(jb + i)*64 + lane] + bo;
      h = fmaxf(h, 0.f);
      int kc = o >> 6, wi = o & 63, slot = wi >> 3, rem = wi & 7;
      *(__bf16*)(H1b + (size_t)r*8192 + kc*128 + (((slot ^ (r & 7)) << 4) | (rem*2))) = (__bf16)h;
    }
  int zi = blockIdx.x*256 + t;
  if (zi < 56*512){
    int r = 200 + (zi >> 9), c = zi & 511;
    *(uint4*)(H1b + (size_t)r*8192 + c*16) = (uint4){0,0,0,0};
  }
}

// ---- k_h2c: fused reduce32 + h2 + classifier via G-trick. grid 64 x 256 -------
// z1[c][j] = relu( sum_s RT[s][c]*G[s][j] + sum_n RT[n][512+c]*Wc1[j][n]
//                  + b2[c]*sum_n Wc1[j][n] + bc1[j] )
// All MLP weight reads from LDS (no serial global-load chains).
__global__ __launch_bounds__(256) void k_h2c(const unsigned short* __restrict__ Cp2,
    const float* __restrict__ G, const float* __restrict__ b2,
    const float* __restrict__ Wc1, const float* __restrict__ bc1,
    const float* __restrict__ Wc2, const float* __restrict__ bc2,
    const float* __restrict__ Wc3, const float* __restrict__ bc3,
    float* __restrict__ out){
  __shared__ float Rc[200*8];
  __shared__ float Tc[200*8];
  __shared__ float W1T[200*101];   // [n][j], pad 101 -> conflict-free
  __shared__ float W1s[100];
  __shared__ float z1[8*100];
  __shared__ float z2[8*50];
  __shared__ float W2sh[5000];
  __shared__ float W3sh[500];
  const int t = threadIdx.x;
  const int c0 = blockIdx.x * 8;
  constexpr size_t PART = (size_t)224*1024;

  // stage MLP weights (coalesced)
  for (int i = t; i < 20000; i += 256){
    int j = i / 200, n = i - j*200;
    W1T[n*101 + j] = Wc1[i];
  }
  for (int i = t; i < 5000; i += 256) W2sh[i] = Wc2[i];
  for (int i = t; i < 500;  i += 256) W3sh[i] = Wc3[i];
  // stage RT columns (reduce 32 partials; 16B coalesced chunks)
  for (int i = t; i < 400; i += 256){
    int s = (i < 200) ? i : i - 200;
    int off = (i < 200) ? c0 : 512 + c0;
    const unsigned short* base = Cp2 + (size_t)s*1024 + off;
    float a[8] = {0.f,0.f,0.f,0.f,0.f,0.f,0.f,0.f};
    #pragma unroll 8
    for (int ks = 0; ks < 32; ks++){
      union { uint4 v; unsigned short u_[8]; } q;
      q.v = *(const uint4*)(base + (size_t)ks*PART);
      #pragma unroll
      for (int j = 0; j < 8; j++) a[j] += bf2f(q.u_[j]);
    }
    float* dst = ((i < 200) ? Rc : Tc) + s*8;
    #pragma unroll
    for (int j = 0; j < 8; j++) dst[j] = a[j];
  }
  __syncthreads();
  if (t < 100){
    float acc = 0.f;
    #pragma unroll 4
    for (int n = 0; n < 200; n++) acc += W1T[n*101 + t];
    W1s[t] = acc;
  }
  __syncthreads();

  // layer 1 (contracts the 200-dim; G global-coalesced, rest LDS)
  for (int task = t; task < 800; task += 256){
    int cc = task / 100, j = task - cc*100;
    float acc = bc1[j] + b2[c0 + cc] * W1s[j];
    #pragma unroll 4
    for (int s = 0; s < 200; s++){
      acc = fmaf(Rc[s*8 + cc], G[(size_t)s*100 + j], acc);
      acc = fmaf(Tc[s*8 + cc], W1T[s*101 + j], acc);
    }
    z1[cc*100 + j] = fmaxf(acc, 0.f);
  }
  __syncthreads();
  // layer 2
  for (int task = t; task < 400; task += 256){
    int cc = task / 50, k = task - cc*50;
    float acc = bc2[k];
    #pragma unroll 4
    for (int j = 0; j < 100; j++)
      acc = fmaf(z1[cc*100 + j], W2sh[k*100 + j], acc);
    z2[cc*50 + k] = fmaxf(acc, 0.f);
  }
  __syncthreads();
  // layer 3
  for (int task = t; task < 80; task += 256){
    int cc = task / 10, m = task - cc*10;
    float acc = bc3[m];
    #pragma unroll
    for (int k = 0; k < 50; k++)
      acc = fmaf(z2[cc*50 + k], W3sh[m*50 + k], acc);
    out[(size_t)(c0 + cc)*10 + m] = acc;
  }
}

// ---------------- host launch ---------------------------------------------------
extern "C" void kernel_launch(void* const* d_in, const int* in_sizes, int n_in,
                              void* d_out, int out_size, void* d_ws, size_t ws_size,
                              hipStream_t stream){
  (void)n_in; (void)out_size; (void)ws_size;
  const float* x   = (const float*)d_in[0];
  const int*   ei  = (const int*)  d_in[1];
  const float* ea  = (const float*)d_in[2];
  const float* W1l = (const float*)d_in[3];
  const float* W1r = (const float*)d_in[4];
  const float* b1  = (const float*)d_in[5];
  const float* W2l = (const float*)d_in[6];
  const float* W2r = (const float*)d_in[7];
  const float* b2  = (const float*)d_in[8];
  const float* Wc1 = (const float*)d_in[9];
  const float* bc1 = (const float*)d_in[10];
  const float* Wc2 = (const float*)d_in[11];
  const float* bc2 = (const float*)d_in[12];
  const float* Wc3 = (const float*)d_in[13];
  const float* bc3 = (const float*)d_in[14];
  float* out = (float*)d_out;
  char* ws = (char*)d_ws;
  const int E = in_sizes[1] / 2;

  constexpr size_t ST_OFF  = 0;                                   // Straw 160000
  constexpr size_t RC_OFF  = 160000;                              // rcnt 800
  constexpr size_t G_OFF   = 161024;                              // G 200x100 f32
  constexpr size_t XB_OFF  = 262144;                              // Xb 8 MiB
  constexpr size_t CP1_OFF = XB_OFF + (size_t)256*16384*2;        // 8 x 224 x 8192 bf16
  constexpr size_t H1B_OFF = CP1_OFF + (size_t)8*224*8192*2;      // 256 x 4096 bf16
  constexpr size_t CP2_OFF = H1B_OFF + (size_t)256*4096*2;        // 32 x 224 x 1024 bf16

  float*          St  = (float*)(ws + ST_OFF);
  float*          rc  = (float*)(ws + RC_OFF);
  float*          Gm  = (float*)(ws + G_OFF);
  unsigned char*  Xb  = (unsigned char*)(ws + XB_OFF);
  unsigned short* Cp1 = (unsigned short*)(ws + CP1_OFF);
  unsigned char*  H1b = (unsigned char*)(ws + H1B_OFF);
  unsigned short* Cp2 = (unsigned short*)(ws + CP2_OFF);

  k_pre<<<dim3(89), dim3(1024), 0, stream>>>(ei, ea, E, St, rc, Wc1, Gm, x, Xb);
  // GEMM1: BN=128, KS=8, NITER=32, NT loads, grid 512 (2 blocks/CU)
  k_gemm<128, 8, 16384, 8192, 32, 256, true><<<dim3(512), dim3(256), 0, stream>>>(Xb, W1l, W1r, Cp1);
  k_h1r<<<dim3(256), dim3(256), 0, stream>>>(Cp1, St, rc, b1, H1b);
  // GEMM2: BN=128, KS=32, NITER=2, grid 256 (1 block/CU)
  k_gemm<128, 32, 4096, 1024, 2, 256, false><<<dim3(256), dim3(256), 0, stream>>>(H1b, W2l, W2r, Cp2);
  k_h2c<<<dim3(64), dim3(256), 0, stream>>>(Cp2, Gm, b2, Wc1, bc1, Wc2, bc2, Wc3, bc3, out);
}